// Round 1
// baseline (576.513 us; speedup 1.0000x reference)
//
#include <hip/hip_runtime.h>
#include <math.h>

#define NROWS 65536
#define DD 64
#define RR 256
#define ZTOT (RR*DD + RR)   // 16640 floats: z[256][64] then ksum[256]

// sc = 64^{-1/4} = 2^{-1.5}
#define SC 0.35355339059327373f
// ln(1/16)
#define LNRATIO -2.772588722239781f

// ---------------- Kernel A: phi(k)^T @ v and sum(phi(k)) partials ----------------
__global__ __launch_bounds__(256, 2)
void favor_kv_kernel(const float* __restrict__ k,
                     const float* __restrict__ v,
                     const float* __restrict__ P,
                     float* __restrict__ partials,   // [nblk][ZTOT]
                     int rowsPerBlock)
{
    const int t = threadIdx.x;      // owns projection row r = t
    const int b = blockIdx.x;

    // Preload scaled projection row into registers (fold sc into P)
    float Preg[64];
    #pragma unroll
    for (int j = 0; j < 64; j += 4) {
        float4 pv = *(const float4*)(P + t * 64 + j);
        Preg[j + 0] = SC * pv.x;
        Preg[j + 1] = SC * pv.y;
        Preg[j + 2] = SC * pv.z;
        Preg[j + 3] = SC * pv.w;
    }

    float zacc[64];
    #pragma unroll
    for (int c = 0; c < 64; c++) zacc[c] = 0.0f;
    float ksum = 0.0f;

    __shared__ float rowconst[128];

    int row0 = b * rowsPerBlock;
    int row1 = row0 + rowsPerBlock;
    if (row1 > NROWS) row1 = NROWS;

    for (int tile = row0; tile < row1; tile += 128) {
        int tn = row1 - tile;
        if (tn > 128) tn = 128;

        // Phase 0: per-row constant  -0.5*||sc*k_row||^2 + ln(ratio)
        if (t < tn) {
            const float4* kr = (const float4*)(k + (size_t)(tile + t) * 64);
            float s0 = 0.f, s1 = 0.f, s2 = 0.f, s3 = 0.f;
            #pragma unroll
            for (int j = 0; j < 16; j += 4) {
                float4 a = kr[j + 0]; s0 += a.x * a.x + a.y * a.y + a.z * a.z + a.w * a.w;
                float4 bq = kr[j + 1]; s1 += bq.x * bq.x + bq.y * bq.y + bq.z * bq.z + bq.w * bq.w;
                float4 cq = kr[j + 2]; s2 += cq.x * cq.x + cq.y * cq.y + cq.z * cq.z + cq.w * cq.w;
                float4 dq = kr[j + 3]; s3 += dq.x * dq.x + dq.y * dq.y + dq.z * dq.z + dq.w * dq.w;
            }
            rowconst[t] = -0.5f * SC * SC * ((s0 + s1) + (s2 + s3)) + LNRATIO;
        }
        __syncthreads();

        for (int i = 0; i < tn; i++) {
            const float* kr = k + (size_t)(tile + i) * 64;   // wave-uniform address
            float d0 = 0.f, d1 = 0.f, d2 = 0.f, d3 = 0.f;
            #pragma unroll
            for (int j = 0; j < 64; j += 4) {
                d0 += kr[j + 0] * Preg[j + 0];
                d1 += kr[j + 1] * Preg[j + 1];
                d2 += kr[j + 2] * Preg[j + 2];
                d3 += kr[j + 3] * Preg[j + 3];
            }
            float phi = __expf((d0 + d1) + (d2 + d3) + rowconst[i]);
            ksum += phi;
            const float* vr = v + (size_t)(tile + i) * 64;   // wave-uniform address
            #pragma unroll
            for (int c = 0; c < 64; c++) zacc[c] += phi * vr[c];
        }
        __syncthreads();
    }

    // Write this block's partial slot (fully written; no zero-init needed)
    float* slot = partials + (size_t)b * ZTOT;
    #pragma unroll
    for (int c = 0; c < 64; c += 4) {
        *(float4*)(slot + t * 64 + c) = make_float4(zacc[c], zacc[c + 1], zacc[c + 2], zacc[c + 3]);
    }
    slot[RR * DD + t] = ksum;
}

// ---------------- Reduce: sum partials -> final z + ksum ----------------
__global__ __launch_bounds__(256)
void favor_reduce_kernel(const float* __restrict__ partials,
                         float* __restrict__ zfinal,
                         int nblk)
{
    int idx = blockIdx.x * 256 + threadIdx.x;   // 65*256 == 16640 exactly
    float s = 0.0f;
    for (int b = 0; b < nblk; b++) s += partials[(size_t)b * ZTOT + idx];
    zfinal[idx] = s;
}

// ---------------- Kernel B: out = diag(1/(phi(q)·ksum)) * phi(q) @ z ----------------
__global__ __launch_bounds__(256, 2)
void favor_out_kernel(const float* __restrict__ q,
                      const float* __restrict__ P,
                      const float* __restrict__ zf,    // z[256*64] then ksum[256]
                      float* __restrict__ out)
{
    const int t = threadIdx.x;
    const int half = t >> 7;        // 0: r in [0,128), 1: r in [128,256)
    const int rl = t & 127;         // local row
    const int row = blockIdx.x * 128 + rl;

    // Load scaled q row, compute row constant (sc folded into qreg)
    float qreg[64];
    float s0 = 0.f, s1 = 0.f, s2 = 0.f, s3 = 0.f;
    #pragma unroll
    for (int j = 0; j < 64; j += 4) {
        float4 qv = *(const float4*)(q + (size_t)row * 64 + j);
        qreg[j + 0] = SC * qv.x; qreg[j + 1] = SC * qv.y;
        qreg[j + 2] = SC * qv.z; qreg[j + 3] = SC * qv.w;
        s0 += qreg[j + 0] * qreg[j + 0];
        s1 += qreg[j + 1] * qreg[j + 1];
        s2 += qreg[j + 2] * qreg[j + 2];
        s3 += qreg[j + 3] * qreg[j + 3];
    }
    const float cst = -0.5f * ((s0 + s1) + (s2 + s3)) + LNRATIO;

    float w[64];
    #pragma unroll
    for (int c = 0; c < 64; c++) w[c] = 0.0f;
    float denom = 0.0f;

    const float* ks = zf + RR * DD;
    const int r0 = half * 128;
    for (int r = r0; r < r0 + 128; r++) {
        const float* Pr = P + r * 64;         // wave-uniform address
        float d0 = 0.f, d1 = 0.f, d2 = 0.f, d3 = 0.f;
        #pragma unroll
        for (int j = 0; j < 64; j += 4) {
            d0 += qreg[j + 0] * Pr[j + 0];
            d1 += qreg[j + 1] * Pr[j + 1];
            d2 += qreg[j + 2] * Pr[j + 2];
            d3 += qreg[j + 3] * Pr[j + 3];
        }
        float phi = __expf((d0 + d1) + (d2 + d3) + cst);
        denom += phi * ks[r];
        const float* zr = zf + r * 64;        // wave-uniform address
        #pragma unroll
        for (int c = 0; c < 64; c++) w[c] += phi * zr[c];
    }

    // Combine the two r-halves through LDS (transposed layout: conflict-free)
    __shared__ float wsh[64 * 128];
    __shared__ float dsh[128];
    if (half) {
        #pragma unroll
        for (int c = 0; c < 64; c++) wsh[c * 128 + rl] = w[c];
        dsh[rl] = denom;
    }
    __syncthreads();
    if (!half) {
        denom += dsh[rl];
        #pragma unroll
        for (int c = 0; c < 64; c++) w[c] += wsh[c * 128 + rl];
        float inv = 1.0f / denom;
        #pragma unroll
        for (int c = 0; c < 64; c += 4) {
            *(float4*)(out + (size_t)row * 64 + c) =
                make_float4(w[c] * inv, w[c + 1] * inv, w[c + 2] * inv, w[c + 3] * inv);
        }
    }
}

extern "C" void kernel_launch(void* const* d_in, const int* in_sizes, int n_in,
                              void* d_out, int out_size, void* d_ws, size_t ws_size,
                              hipStream_t stream) {
    const float* q = (const float*)d_in[0];
    const float* k = (const float*)d_in[1];
    const float* v = (const float*)d_in[2];
    const float* P = (const float*)d_in[3];
    float* out = (float*)d_out;

    float* zfinal = (float*)d_ws;            // ZTOT floats
    float* partials = zfinal + ZTOT;

    long availFloats = (long)(ws_size / 4);
    long slots = (availFloats - (long)ZTOT) / (long)ZTOT;
    int nblk = (int)(slots < 512 ? slots : 512);
    if (nblk < 1) nblk = 1;
    int rpb = (NROWS + nblk - 1) / nblk;

    favor_kv_kernel<<<nblk, 256, 0, stream>>>(k, v, P, partials, rpb);
    favor_reduce_kernel<<<65, 256, 0, stream>>>(partials, zfinal, nblk);
    favor_out_kernel<<<512, 256, 0, stream>>>(q, P, zfinal, out);
}